// Round 14
// baseline (82.901 us; speedup 1.0000x reference)
//
#include <hip/hip_runtime.h>
#include <hip/hip_cooperative_groups.h>
#include <math.h>

namespace cg = cooperative_groups;

#define BB 32
#define NN 512
#define NFEAT 128
#define NHID 8
#define NHEADS 8
#define LALPHA 0.2f

__device__ __forceinline__ float elu1(float x)  { return x > 0.f ? x : __expf(x) - 1.f; }

__device__ __forceinline__ unsigned ordkey(float v) {
    unsigned u = __float_as_uint(v);
    return u ^ (((unsigned)((int)u >> 31)) | 0x80000000u);
}
__device__ __forceinline__ float unord(unsigned k) {
    unsigned u = (k & 0x80000000u) ? (k ^ 0x80000000u) : ~k;
    return __uint_as_float(u);
}

#if __has_builtin(__builtin_amdgcn_update_dpp)
__device__ __forceinline__ float wscan(float x, int lane) {
    int y;
    y = __builtin_amdgcn_update_dpp(0, __float_as_int(x), 0x111, 0xF, 0xF, true); x += __int_as_float(y);
    y = __builtin_amdgcn_update_dpp(0, __float_as_int(x), 0x112, 0xF, 0xF, true); x += __int_as_float(y);
    y = __builtin_amdgcn_update_dpp(0, __float_as_int(x), 0x114, 0xF, 0xF, true); x += __int_as_float(y);
    y = __builtin_amdgcn_update_dpp(0, __float_as_int(x), 0x118, 0xF, 0xF, true); x += __int_as_float(y);
    y = __builtin_amdgcn_update_dpp(0, __float_as_int(x), 0x142, 0xA, 0xF, true); x += __int_as_float(y);
    y = __builtin_amdgcn_update_dpp(0, __float_as_int(x), 0x143, 0xC, 0xF, true); x += __int_as_float(y);
    return x;
}
#else
__device__ __forceinline__ float wscan(float x, int lane) {
    #pragma unroll
    for (int s = 1; s < 64; s <<= 1) {
        float y = __shfl_up(x, (unsigned)s, 64);
        x += (lane >= s) ? y : 0.f;
    }
    return x;
}
#endif

__device__ __forceinline__ unsigned long long shflxor64(unsigned long long x, int j) {
    unsigned lo = (unsigned)__shfl_xor((int)(unsigned)x, j, 64);
    unsigned hw = (unsigned)__shfl_xor((int)(unsigned)(x >> 32), j, 64);
    return (((unsigned long long)hw) << 32) | lo;
}

__device__ __forceinline__ unsigned long long wsort64(unsigned long long x, int lane) {
    #pragma unroll
    for (int k = 2; k <= 64; k <<= 1) {
        #pragma unroll
        for (int j = k >> 1; j >= 1; j >>= 1) {
            unsigned long long y = shflxor64(x, j);
            const bool takeMin = ((lane & j) == 0) == ((lane & k) == 0);
            const bool sw = takeMin ? (y < x) : (x < y);
            x = sw ? y : x;
        }
    }
    return x;
}

__device__ __forceinline__ int lb64u(const unsigned long long* a, unsigned long long v) {
    int lo = 0;
    #pragma unroll
    for (int s = 64; s >= 1; s >>= 1) {
        const int i2 = lo + s - 1;
        if (i2 < 64 && a[i2] < v) lo += s;
    }
    return lo;
}
__device__ __forceinline__ int lb512u(const unsigned long long* a, unsigned long long v) {
    int lo = 0;
    #pragma unroll
    for (int s = NN; s >= 1; s >>= 1) {
        const int i2 = lo + s - 1;
        if (i2 < NN && a[i2] < v) lo += s;
    }
    return lo;
}

__device__ __forceinline__ int rank512(const unsigned long long* runs, unsigned long long x,
                                       int wr, int lane) {
    int rk = lane;
    #pragma unroll
    for (int w2 = 0; w2 < 8; ++w2)
        if (w2 != wr) rk += lb64u(runs + 64 * w2, x);
    return rk;
}

// One cooperative kernel. Phase A (all 256 blocks): layer-1 GAT per (b,h), then each
// block applies its 8x8 W_out slice and writes a partial Wh2 (512x8) to ws.
// grid.sync. Phase B (blocks 0..31): reduce 8 partials -> Wh2/s1/s2, sort, factorized
// row-0 attention, head MLP -> out[b]. LDS ~92 KB -> 1 block/CU (no VGPR cap / spills).
__global__ __launch_bounds__(1024) void fused_gat(
        const float* __restrict__ nf, const float* __restrict__ Ws,
        const float* __restrict__ As, const float* __restrict__ Wout,
        const float* __restrict__ aout, const float* __restrict__ feats,
        const float* __restrict__ l1w, const float* __restrict__ l1b,
        const float* __restrict__ pa, const float* __restrict__ gma,
        const float* __restrict__ bta, const float* __restrict__ l2w,
        const float* __restrict__ l2b, float* __restrict__ out,
        float* __restrict__ part2)
{
    __shared__ __align__(16) float WT[NHID * NFEAT];           // 4 KB
    __shared__ float aL[16];
    __shared__ float WoL[64];                                  // W_out slice for head h
    __shared__ __align__(16) float whL[NN][NHID];              // 16 KB (phase B: Wh2)
    __shared__ __align__(16) float part[NN][NHID];             // 16 KB
    __shared__ __align__(16) unsigned long long key1L[NN];     // 4 KB
    __shared__ __align__(16) unsigned long long key2L[NN];     // 4 KB
    __shared__ __align__(16) unsigned long long keyR1[NN];     // 4 KB
    __shared__ __align__(16) unsigned long long keyR2[NN];     // 4 KB
    __shared__ float s2L[NN];                                  // 2 KB (phase B)
    __shared__ float prefP[NN], prefQ[NN], denS[NN];           // 6 KB
    __shared__ __align__(16) float PP[NN][NHID];               // 16 KB
    __shared__ __align__(16) float QQ[NN][NHID];               // 16 KB
    __shared__ __align__(16) float wvT[16][NHID];              // 0.5 KB
    __shared__ float wR[8][NHID];
    __shared__ float hp[2][NHID];
    __shared__ float gatL[NHID];
    __shared__ float zL[NHID];
    __shared__ float s1zero;

    const int blk = blockIdx.x;
    const int b = blk & 31, h = blk >> 5;   // XCD swizzle: blk%8 == b%8
    const int t = threadIdx.x;
    const int r = t & (NN - 1);
    const bool hi = t >= NN;
    const int lane = t & 63, w = t >> 6;
    const int wr = w & 7;

    // ================= Phase A: layer-1 GAT per (b,h) =================
    {
        const int f = t >> 3, d = t & 7;
        WT[d * NFEAT + f] = Ws[(size_t)h * NFEAT * NHID + t];
    }
    if (t < 16) aL[t] = As[h * 16 + t];
    if (t >= 960) WoL[t - 960] = Wout[h * 64 + (t - 960)];
    __syncthreads();                                           // A1

    float acc[NHID];
    {
        #pragma unroll
        for (int d = 0; d < NHID; ++d) acc[d] = 0.f;
        const float4* row = (const float4*)(nf + ((size_t)b * NN + r) * NFEAT + (hi ? 64 : 0));
        const int fb = hi ? 16 : 0;
        const float4* WT4 = (const float4*)WT;
        #pragma unroll 4
        for (int f4 = 0; f4 < 16; ++f4) {
            float4 v = row[f4];
            #pragma unroll
            for (int d = 0; d < NHID; ++d) {
                float4 wv = WT4[d * 32 + fb + f4];
                acc[d] += v.x * wv.x + v.y * wv.y + v.z * wv.z + v.w * wv.w;
            }
        }
        if (hi) {
            float4* pp = (float4*)&part[r][0];
            pp[0] = make_float4(acc[0], acc[1], acc[2], acc[3]);
            pp[1] = make_float4(acc[4], acc[5], acc[6], acc[7]);
        }
    }
    __syncthreads();                                           // A2

    float v1 = 0.f;
    unsigned long long sk = 0ull;
    if (!hi) {
        #pragma unroll
        for (int d = 0; d < NHID; ++d) acc[d] += part[t][d];
        float a1 = 0.f, a2 = 0.f;
        #pragma unroll
        for (int d = 0; d < NHID; ++d) { a1 += acc[d] * aL[d]; a2 += acc[d] * aL[8 + d]; }
        v1 = a1;
        float4* wrp = (float4*)&whL[t][0];
        wrp[0] = make_float4(acc[0], acc[1], acc[2], acc[3]);
        wrp[1] = make_float4(acc[4], acc[5], acc[6], acc[7]);
        sk = (((unsigned long long)ordkey(a1)) << 9) | (unsigned)t;
        key2L[t] = (((unsigned long long)ordkey(a2)) << 9) | (unsigned)t;
    }
    __syncthreads();                                           // A3

    if (hi) sk = key2L[r];
    sk = wsort64(sk, lane);
    if (!hi) keyR1[t] = sk; else keyR2[r] = sk;
    __syncthreads();                                           // A4

    {
        const unsigned long long* runs = hi ? keyR2 : keyR1;
        const int rk = rank512(runs, sk, wr, lane);
        if (!hi) key1L[rk] = sk; else key2L[rk] = sk;
    }
    __syncthreads();                                           // A5

    float ps = 0.f, qs = 0.f;
    float who[NHID];
    float s2r = 0.f, e2p = 0.f, e2q = 0.f, e1p = 0.f, e1q = 0.f;
    int kH = 0, c4 = 0;
    if (!hi) {
        const float s1v = unord((unsigned)(key1L[t] >> 9));
        ps = wscan(__expf(s1v), lane);
        qs = wscan(__expf(LALPHA * s1v), lane);
        if (lane == 63) { wvT[w][0] = ps; wvT[w][1] = qs; }
        c4 = lb512u(key2L, ((unsigned long long)(~ordkey(v1))) << 9);
        e1p = __expf(v1); e1q = __expf(LALPHA * v1);
    } else {
        const unsigned long long k2 = key2L[r];
        s2r = unord((unsigned)(k2 >> 9));
        const int j = (int)(k2 & 511u);
        const float4 w0 = ((const float4*)&whL[j][0])[0];
        const float4 w1 = ((const float4*)&whL[j][0])[1];
        who[0] = w0.x; who[1] = w0.y; who[2] = w0.z; who[3] = w0.w;
        who[4] = w1.x; who[5] = w1.y; who[6] = w1.z; who[7] = w1.w;
        kH = lb512u(key1L, ((unsigned long long)(~(unsigned)(k2 >> 9))) << 9);
        e2p = __expf(s2r); e2q = __expf(LALPHA * s2r);
    }
    __syncthreads();                                           // A6

    float pw = 0.f;
    if (!hi) {
        float offp = 0.f, offq = 0.f;
        #pragma unroll
        for (int ww = 0; ww < 8; ++ww) {
            const float tp = wvT[ww][0], tq = wvT[ww][1];
            if (ww < w) { offp += tp; offq += tq; }
        }
        prefP[t] = ps + offp;
        prefQ[t] = qs + offq;
        const unsigned long long k2 = key2L[t];
        const float s2p = unord((unsigned)(k2 >> 9));
        const int j2 = (int)(k2 & 511u);
        const float4 w0 = ((const float4*)&whL[j2][0])[0];
        const float4 w1 = ((const float4*)&whL[j2][0])[1];
        who[0] = w0.x; who[1] = w0.y; who[2] = w0.z; who[3] = w0.w;
        who[4] = w1.x; who[5] = w1.y; who[6] = w1.z; who[7] = w1.w;
        pw = __expf(s2p);
    }
    __syncthreads();                                           // A7

    if (hi) {
        const float TPh = prefP[NN - 1];
        const float pk = kH ? prefP[kH - 1] : 0.f;
        const float qk = kH ? prefQ[kH - 1] : 0.f;
        const float den = e2p * (TPh - pk) + e2q * qk;
        denS[r] = den;
        pw = e2q / den;
    }
    __syncthreads();                                           // A8

    float pv[NHID];
    if (!hi) pw /= denS[t];
    #pragma unroll
    for (int c = 0; c < NHID; ++c) pv[c] = wscan(pw * who[c], lane);
    if (lane == 63) {
        float4* wp = (float4*)&wvT[w][0];
        wp[0] = make_float4(pv[0], pv[1], pv[2], pv[3]);
        wp[1] = make_float4(pv[4], pv[5], pv[6], pv[7]);
    }
    __syncthreads();                                           // A9

    float tot[NHID];
    {
        const int wb = hi ? 8 : 0;
        float off[NHID];
        #pragma unroll
        for (int c = 0; c < NHID; ++c) { off[c] = 0.f; tot[c] = 0.f; }
        #pragma unroll
        for (int ww = 0; ww < 8; ++ww) {
            const float4 t0 = ((const float4*)&wvT[wb + ww][0])[0];
            const float4 t1 = ((const float4*)&wvT[wb + ww][0])[1];
            tot[0] += t0.x; tot[1] += t0.y; tot[2] += t0.z; tot[3] += t0.w;
            tot[4] += t1.x; tot[5] += t1.y; tot[6] += t1.z; tot[7] += t1.w;
            if (wb + ww < w) {
                off[0] += t0.x; off[1] += t0.y; off[2] += t0.z; off[3] += t0.w;
                off[4] += t1.x; off[5] += t1.y; off[6] += t1.z; off[7] += t1.w;
            }
        }
        #pragma unroll
        for (int c = 0; c < NHID; ++c) pv[c] += off[c];
        float4* dst = hi ? (float4*)&QQ[r][0] : (float4*)&PP[r][0];
        dst[0] = make_float4(pv[0], pv[1], pv[2], pv[3]);
        dst[1] = make_float4(pv[4], pv[5], pv[6], pv[7]);
    }
    __syncthreads();                                           // A10

    // P: row outputs -> elu -> 8x8 W_out slice -> partial Wh2 (coalesced, 32 B/lane)
    if (!hi) {
        float4 P0, P1, Q0, Q1;
        if (c4 > 0) {
            const float4* pp4 = (const float4*)&PP[c4 - 1][0];
            const float4* qq4 = (const float4*)&QQ[c4 - 1][0];
            P0 = pp4[0]; P1 = pp4[1]; Q0 = qq4[0]; Q1 = qq4[1];
        } else {
            P0 = P1 = Q0 = Q1 = make_float4(0.f, 0.f, 0.f, 0.f);
        }
        float xk[NHID];
        xk[0] = elu1(e1p * (tot[0] - P0.x) + e1q * Q0.x);
        xk[1] = elu1(e1p * (tot[1] - P0.y) + e1q * Q0.y);
        xk[2] = elu1(e1p * (tot[2] - P0.z) + e1q * Q0.z);
        xk[3] = elu1(e1p * (tot[3] - P0.w) + e1q * Q0.w);
        xk[4] = elu1(e1p * (tot[4] - P1.x) + e1q * Q1.x);
        xk[5] = elu1(e1p * (tot[5] - P1.y) + e1q * Q1.y);
        xk[6] = elu1(e1p * (tot[6] - P1.z) + e1q * Q1.z);
        xk[7] = elu1(e1p * (tot[7] - P1.w) + e1q * Q1.w);
        float pd[NHID];
        #pragma unroll
        for (int d = 0; d < NHID; ++d) pd[d] = 0.f;
        #pragma unroll
        for (int k = 0; k < NHID; ++k) {
            const float xv = xk[k];
            #pragma unroll
            for (int d = 0; d < NHID; ++d) pd[d] += xv * WoL[k * NHID + d];
        }
        float4* dst = (float4*)(part2 + (((size_t)(b * NHEADS + h)) * NN + t) * NHID);
        dst[0] = make_float4(pd[0], pd[1], pd[2], pd[3]);
        dst[1] = make_float4(pd[4], pd[5], pd[6], pd[7]);
    }

    cg::this_grid().sync();                                    // ======== grid sync ========

    // ================= Phase B: tail, blocks 0..31 (b2 = blk) =================
    if (blk >= BB) return;
    const int b2 = blk;

    if (t < 16) aL[t] = aout[t];
    __syncthreads();                                           // B1

    unsigned long long sk2 = 0ull;
    if (!hi) {
        // reduce 8 head-partials -> Wh2 row t (reads hit own XCD's L2)
        float wv[NHID];
        #pragma unroll
        for (int d = 0; d < NHID; ++d) wv[d] = 0.f;
        #pragma unroll
        for (int hh = 0; hh < NHEADS; ++hh) {
            const float4* src = (const float4*)(part2 + (((size_t)(b2 * NHEADS + hh)) * NN + t) * NHID);
            const float4 p0 = src[0], p1 = src[1];
            wv[0] += p0.x; wv[1] += p0.y; wv[2] += p0.z; wv[3] += p0.w;
            wv[4] += p1.x; wv[5] += p1.y; wv[6] += p1.z; wv[7] += p1.w;
        }
        float a1 = 0.f, a2 = 0.f;
        #pragma unroll
        for (int d = 0; d < NHID; ++d) { a1 += wv[d] * aL[d]; a2 += wv[d] * aL[8 + d]; }
        float4* wrp = (float4*)&whL[t][0];
        wrp[0] = make_float4(wv[0], wv[1], wv[2], wv[3]);
        wrp[1] = make_float4(wv[4], wv[5], wv[6], wv[7]);
        sk2 = (((unsigned long long)ordkey(a1)) << 9) | (unsigned)t;
        s2L[t] = a2;
        if (t == 0) s1zero = a1;
    } else if (r < 128) {
        const float fk = feats[b2 * NFEAT + r];
        #pragma unroll
        for (int d = 0; d < NHID; ++d) {
            float p = fk * l1w[d * (NFEAT + NHID) + r];
            #pragma unroll
            for (int s = 1; s < 64; s <<= 1) p += __shfl_xor(p, s, 64);
            if (lane == 0) hp[w - 8][d] = p;
        }
    }
    __syncthreads();                                           // B2

    if (!hi) {
        sk2 = wsort64(sk2, lane);
        keyR1[t] = sk2;
    }
    __syncthreads();                                           // B3

    if (!hi) {
        const int rk = rank512(keyR1, sk2, wr, lane);
        key1L[rk] = sk2;
    }
    __syncthreads();                                           // B4

    float ps2 = 0.f, qs2 = 0.f;
    int c3 = 0; float v2h = 0.f, f2p = 0.f, f2q = 0.f;
    if (!hi) {
        const float s1v = unord((unsigned)(key1L[t] >> 9));
        ps2 = wscan(__expf(s1v), lane);
        qs2 = wscan(__expf(LALPHA * s1v), lane);
        if (lane == 63) { wvT[w][0] = ps2; wvT[w][1] = qs2; }
    } else {
        v2h = s2L[r];
        c3 = lb512u(key1L, ((unsigned long long)(~ordkey(v2h))) << 9);
        f2p = __expf(v2h); f2q = __expf(LALPHA * v2h);
    }
    __syncthreads();                                           // B5

    if (!hi) {
        float offp = 0.f, offq = 0.f;
        #pragma unroll
        for (int ww = 0; ww < 8; ++ww) {
            const float tp = wvT[ww][0], tq = wvT[ww][1];
            if (ww < w) { offp += tp; offq += tq; }
        }
        prefP[t] = ps2 + offp;
        prefQ[t] = qs2 + offq;
    }
    __syncthreads();                                           // B6

    if (hi) {
        const float TPh = prefP[NN - 1];
        const float pk = c3 ? prefP[c3 - 1] : 0.f;
        const float qk = c3 ? prefQ[c3 - 1] : 0.f;
        const float dj = f2p * (TPh - pk) + f2q * qk;
        float e0 = s1zero + v2h;
        e0 = e0 >= 0.f ? e0 : LALPHA * e0;
        const float wgt = __expf(e0) / dj;
        float a[NHID];
        const float4 q0 = ((const float4*)&whL[r][0])[0];
        const float4 q1 = ((const float4*)&whL[r][0])[1];
        a[0] = wgt * q0.x; a[1] = wgt * q0.y; a[2] = wgt * q0.z; a[3] = wgt * q0.w;
        a[4] = wgt * q1.x; a[5] = wgt * q1.y; a[6] = wgt * q1.z; a[7] = wgt * q1.w;
        #pragma unroll
        for (int s = 1; s < 64; s <<= 1) {
            #pragma unroll
            for (int d = 0; d < NHID; ++d) a[d] += __shfl_xor(a[d], s, 64);
        }
        if (lane == 0) {
            #pragma unroll
            for (int d = 0; d < NHID; ++d) wR[w - 8][d] = a[d];
        }
    }
    __syncthreads();                                           // B7

    if (t < NHID) {
        float g = 0.f;
        #pragma unroll
        for (int ww = 0; ww < 8; ++ww) g += wR[ww][t];
        gatL[t] = elu1(g);
    }
    __syncthreads();                                           // B8

    if (t < NHID) {
        const float* wv = l1w + t * (NFEAT + NHID);
        float z = l1b[t] + hp[0][t] + hp[1][t];
        #pragma unroll
        for (int k = 0; k < NHID; ++k) z += gatL[k] * wv[NFEAT + k];
        const float a = pa[0];
        z = z >= 0.f ? z : a * z;
        z = z * (1.f / sqrtf(1.f + 1e-5f)) * gma[t] + bta[t];
        zL[t] = z;
    }
    __syncthreads();                                           // B9
    if (t == 0) {
        float o = l2b[0];
        #pragma unroll
        for (int d = 0; d < NHID; ++d) o += zL[d] * l2w[d];
        out[b2] = o;
    }
}

extern "C" void kernel_launch(void* const* d_in, const int* in_sizes, int n_in,
                              void* d_out, int out_size, void* d_ws, size_t ws_size,
                              hipStream_t stream) {
    const float* feats = (const float*)d_in[0];
    const float* nf    = (const float*)d_in[1];
    const float* Ws    = (const float*)d_in[2];
    const float* As    = (const float*)d_in[3];
    const float* Wout  = (const float*)d_in[4];
    const float* aout  = (const float*)d_in[5];
    const float* l1w   = (const float*)d_in[6];
    const float* l1b   = (const float*)d_in[7];
    const float* pa    = (const float*)d_in[8];
    const float* gma   = (const float*)d_in[9];
    const float* bta   = (const float*)d_in[10];
    const float* l2w   = (const float*)d_in[11];
    const float* l2b   = (const float*)d_in[12];
    float* out = (float*)d_out;

    float* part2 = (float*)d_ws;   // 32*8*512*8 floats = 4 MB of partial Wh2

    void* kargs[] = {
        (void*)&nf, (void*)&Ws, (void*)&As, (void*)&Wout, (void*)&aout,
        (void*)&feats, (void*)&l1w, (void*)&l1b, (void*)&pa, (void*)&gma,
        (void*)&bta, (void*)&l2w, (void*)&l2b, (void*)&out, (void*)&part2
    };
    hipLaunchCooperativeKernel((void*)fused_gat, dim3(BB * NHEADS), dim3(1024),
                               kargs, 0, stream);
}